// Round 1
// baseline (572.123 us; speedup 1.0000x reference)
//
#include <hip/hip_runtime.h>
#include <math.h>

// Problem constants (match reference)
#define KB 16      // batch
#define KT 256     // num_tf
#define KG 1024    // num_genes
#define KP 16      // peaks per gene
#define KN 4096    // num_gos
#define KGO 6      // go_dim
#define KH 2       // heads
#define KC 4       // out channels
#define KE 65536   // edges
#define KOUT 32    // num outputs

__device__ __forceinline__ float lrelu(float x, float s) { return x >= 0.f ? x : s * x; }

// ---------------------------------------------------------------------------
// K0: detect edge_index dtype. int64 little-endian with values <2^31 has all
// odd int32 words == 0. Writes flag=1 for int64 mode, 0 for int32.
// ---------------------------------------------------------------------------
__global__ __launch_bounds__(256) void k0_detect(const int* __restrict__ e32,
                                                 int* __restrict__ flag) {
    __shared__ int nz;
    if (threadIdx.x == 0) nz = 0;
    __syncthreads();
    int any = 0;
#pragma unroll
    for (int k = 0; k < 4; ++k) {
        int idx = (threadIdx.x * 4 + k) * 2 + 1;  // odd words of first 1024 entries
        any |= (e32[idx] != 0) ? 1 : 0;
    }
    if (any) atomicOr(&nz, 1);
    __syncthreads();
    if (threadIdx.x == 0) flag[0] = (nz == 0) ? 1 : 0;
}

// ---------------------------------------------------------------------------
// K1: per-gene subnet. One wave per (b,g): 4096-elem dot of x[b,:,g,:] with
// W_sub[g]. x read 100% coalesced in 64B chunks; W_sub contiguous per gene.
// Output layout xcat[b][g] (b-major) for K2's register preload.
// ---------------------------------------------------------------------------
__global__ __launch_bounds__(256) void k1_subnet(const float* __restrict__ x,
                                                 const float* __restrict__ Wsub,
                                                 const float* __restrict__ bsub,
                                                 float* __restrict__ xcat) {
    int wave = blockIdx.x * 4 + (threadIdx.x >> 6);
    int lane = threadIdx.x & 63;
    int b = wave >> 10;        // wave / G
    int g = wave & 1023;       // wave % G
    const float* xb = x + (size_t)b * (KT * KG * KP) + (size_t)g * KP;
    const float* wg = Wsub + (size_t)g * (KT * KP);
    float4 acc = make_float4(0.f, 0.f, 0.f, 0.f);
#pragma unroll 4
    for (int i = 0; i < 16; ++i) {
        int q = lane + 64 * i;         // q in [0,1024): float4 chunk id
        int t = q >> 2;
        int p4 = (q & 3) * 4;
        float4 xv = *(const float4*)(xb + (size_t)t * (KG * KP) + p4);
        float4 wv = *(const float4*)(wg + q * 4);
        acc.x += xv.x * wv.x; acc.y += xv.y * wv.y;
        acc.z += xv.z * wv.z; acc.w += xv.w * wv.w;
    }
    float s = acc.x + acc.y + acc.z + acc.w;
#pragma unroll
    for (int off = 32; off > 0; off >>= 1) s += __shfl_down(s, off, 64);
    if (lane == 0) xcat[b * KG + g] = lrelu(s + bsub[g], 0.01f);
}

// ---------------------------------------------------------------------------
// K2: masked fc1 (the 200 MB stream). Block = 4 waves; wave `wid` owns batches
// b0=wid*4..+3 and preloads its x_cat slice (4 b x 1024 g / 64 lanes = 64
// floats) into registers ONCE. Inner loop per row j: two coalesced float4
// streams (w, mask), 64 FMAs, 24 shfl for the cross-lane reduce. No LDS.
// 4 waves of a block share the same w rows -> L1/L2 hits, HBM reads w once.
// ---------------------------------------------------------------------------
__global__ __launch_bounds__(256) void k2_fc1(const float* __restrict__ w,
                                              const float* __restrict__ mask,
                                              const float* __restrict__ bias,
                                              const float* __restrict__ xcat, // [b][g]
                                              float* __restrict__ ht) {      // [n][b][d]
    int wid = threadIdx.x >> 6;
    int lane = threadIdx.x & 63;
    int b0 = wid * 4;
    float4 xcr[4][4];  // [bb][i] -> x_cat[b0+bb][i*256 + lane*4 .. +3]
#pragma unroll
    for (int bb = 0; bb < 4; ++bb)
#pragma unroll
        for (int i = 0; i < 4; ++i)
            xcr[bb][i] = *(const float4*)(xcat + (b0 + bb) * KG + i * 256 + lane * 4);

    for (int r = 0; r < 16; ++r) {
        int j = blockIdx.x * 16 + r;        // row of (w*mask), j < 24576
        const float* wr = w + (size_t)j * KG;
        const float* mr = mask + (size_t)j * KG;
        float acc0 = 0.f, acc1 = 0.f, acc2 = 0.f, acc3 = 0.f;
#pragma unroll
        for (int i = 0; i < 4; ++i) {
            float4 wv = *(const float4*)(wr + i * 256 + lane * 4);
            float4 mv = *(const float4*)(mr + i * 256 + lane * 4);
            float px = wv.x * mv.x, py = wv.y * mv.y, pz = wv.z * mv.z, pw = wv.w * mv.w;
            acc0 += px * xcr[0][i].x + py * xcr[0][i].y + pz * xcr[0][i].z + pw * xcr[0][i].w;
            acc1 += px * xcr[1][i].x + py * xcr[1][i].y + pz * xcr[1][i].z + pw * xcr[1][i].w;
            acc2 += px * xcr[2][i].x + py * xcr[2][i].y + pz * xcr[2][i].z + pw * xcr[2][i].w;
            acc3 += px * xcr[3][i].x + py * xcr[3][i].y + pz * xcr[3][i].z + pw * xcr[3][i].w;
        }
#pragma unroll
        for (int m = 1; m < 64; m <<= 1) {
            acc0 += __shfl_xor(acc0, m, 64);
            acc1 += __shfl_xor(acc1, m, 64);
            acc2 += __shfl_xor(acc2, m, 64);
            acc3 += __shfl_xor(acc3, m, 64);
        }
        if (lane == 0) {
            float bj = bias[j];
            int d = j >> 12;           // j / N
            int n = j & 4095;          // j % N
            float* hp = ht + ((size_t)n * KB) * KGO + d;
            hp[(b0 + 0) * KGO] = lrelu(acc0 + bj, 0.01f);
            hp[(b0 + 1) * KGO] = lrelu(acc1 + bj, 0.01f);
            hp[(b0 + 2) * KGO] = lrelu(acc2 + bj, 0.01f);
            hp[(b0 + 3) * KGO] = lrelu(acc3 + bj, 0.01f);
        }
    }
}

// ---------------------------------------------------------------------------
// K3: hn = h @ gat_weight, plus attention dot products s_i, s_j per node.
// One thread per (n,b).
// ---------------------------------------------------------------------------
__global__ __launch_bounds__(256) void k3_gatw(const float* __restrict__ ht,
                                               const float* __restrict__ gw,   // [6][8]
                                               const float* __restrict__ att,  // [2][8]
                                               float* __restrict__ hn,         // [n][b][h][c]
                                               float* __restrict__ si,
                                               float* __restrict__ sj) {
    __shared__ float cgw[48];
    __shared__ float catt[16];
    int t = threadIdx.x;
    if (t < 48) cgw[t] = gw[t];
    else if (t < 64) catt[t - 48] = att[t - 48];
    __syncthreads();
    int idx = blockIdx.x * 256 + t;  // n*16 + b
    float h6[6];
#pragma unroll
    for (int d = 0; d < 6; ++d) h6[d] = ht[(size_t)idx * KGO + d];
    float o[8];
#pragma unroll
    for (int hc = 0; hc < 8; ++hc) {
        float v = 0.f;
#pragma unroll
        for (int d = 0; d < 6; ++d) v += h6[d] * cgw[d * 8 + hc];
        o[hc] = v;
        hn[(size_t)idx * 8 + hc] = v;
    }
#pragma unroll
    for (int hh = 0; hh < 2; ++hh) {
        float vi = 0.f, vj = 0.f;
#pragma unroll
        for (int c = 0; c < 4; ++c) {
            vi += o[hh * 4 + c] * catt[hh * 8 + c];       // att[:, :C]  (x_i)
            vj += o[hh * 4 + c] * catt[hh * 8 + 4 + c];   // att[:, C:]  (x_j)
        }
        si[idx * 2 + hh] = vi;
        sj[idx * 2 + hh] = vj;
    }
}

// ---------------------------------------------------------------------------
// K4a/b/c: CSR build (histogram, exclusive scan, scatter)
// ---------------------------------------------------------------------------
__global__ __launch_bounds__(256) void k4a_hist(const int* __restrict__ e32,
                                                const int* __restrict__ flag,
                                                int* __restrict__ cnt) {
    int e = blockIdx.x * 256 + threadIdx.x;
    int mode = flag[0];
    int d = mode ? e32[2 * (KE + e)] : e32[KE + e];
    atomicAdd(&cnt[d], 1);
}

__global__ __launch_bounds__(1024) void k4b_scan(const int* __restrict__ cnt,
                                                 int* __restrict__ off,
                                                 int* __restrict__ cur) {
    __shared__ int buf[2][1024];
    int t = threadIdx.x;
    int c0 = cnt[t * 4 + 0], c1 = cnt[t * 4 + 1], c2 = cnt[t * 4 + 2], c3 = cnt[t * 4 + 3];
    int s = c0 + c1 + c2 + c3;
    buf[0][t] = s;
    __syncthreads();
    int pb = 0;
    for (int d = 1; d < 1024; d <<= 1) {
        int v = buf[pb][t];
        if (t >= d) v += buf[pb][t - d];
        buf[1 - pb][t] = v;
        pb = 1 - pb;
        __syncthreads();
    }
    int incl = buf[pb][t];
    int base = incl - s;  // exclusive prefix
    int o0 = base, o1 = base + c0, o2 = base + c0 + c1, o3 = base + c0 + c1 + c2;
    off[t * 4 + 0] = o0; off[t * 4 + 1] = o1; off[t * 4 + 2] = o2; off[t * 4 + 3] = o3;
    cur[t * 4 + 0] = o0; cur[t * 4 + 1] = o1; cur[t * 4 + 2] = o2; cur[t * 4 + 3] = o3;
    if (t == 1023) off[KN] = incl;
}

__global__ __launch_bounds__(256) void k4c_scatter(const int* __restrict__ e32,
                                                   const int* __restrict__ flag,
                                                   int* __restrict__ cur,
                                                   int* __restrict__ csr) {
    int e = blockIdx.x * 256 + threadIdx.x;
    int mode = flag[0];
    int d = mode ? e32[2 * (KE + e)] : e32[KE + e];
    int s = mode ? e32[2 * e] : e32[e];
    int p = atomicAdd(&cur[d], 1);
    csr[p] = s;
}

// ---------------------------------------------------------------------------
// K5: per-destination-node GAT aggregation. Block per node n; thread groups
// of 8 own one (b,h) pair. Pass 1: segment max (exact, like reference).
// Pass 2: exp-sum + weighted accumulation of hn[src]. Softmax-normalize,
// divide by degree, mean over heads, + bias. Output aggr[b][c*N + n].
// ---------------------------------------------------------------------------
__global__ __launch_bounds__(256) void k5_gat(const int* __restrict__ offs,
                                              const int* __restrict__ csr,
                                              const float* __restrict__ si,
                                              const float* __restrict__ sj,
                                              const float* __restrict__ hn,
                                              const float* __restrict__ gbias,
                                              float* __restrict__ aggr) {
    int n = blockIdx.x;
    int t = threadIdx.x;
    int p = t >> 3;          // (b,h) pair, 0..31
    int s = t & 7;
    int b = p >> 1, h = p & 1;
    int off = offs[n];
    int deg = offs[n + 1] - off;
    __shared__ float red[32][4];
    float l = 0.f, a0 = 0.f, a1 = 0.f, a2 = 0.f, a3 = 0.f;
    if (deg > 0) {
        float sib = si[(n * KB + b) * 2 + h];
        float m = -1e30f;
        for (int i = s; i < deg; i += 8) {
            int sv = csr[off + i];
            float a = sib + sj[(sv * KB + b) * 2 + h];
            a = a >= 0.f ? a : 0.2f * a;
            m = fmaxf(m, a);
        }
        m = fmaxf(m, __shfl_xor(m, 1, 64));
        m = fmaxf(m, __shfl_xor(m, 2, 64));
        m = fmaxf(m, __shfl_xor(m, 4, 64));
        for (int i = s; i < deg; i += 8) {
            int sv = csr[off + i];
            float a = sib + sj[(sv * KB + b) * 2 + h];
            a = a >= 0.f ? a : 0.2f * a;
            float wgt = expf(a - m);
            l += wgt;
            float4 hv = *(const float4*)(hn + ((size_t)(sv * KB + b)) * 8 + h * 4);
            a0 += wgt * hv.x; a1 += wgt * hv.y; a2 += wgt * hv.z; a3 += wgt * hv.w;
        }
#pragma unroll
        for (int d = 1; d <= 4; d <<= 1) {
            l  += __shfl_xor(l,  d, 64);
            a0 += __shfl_xor(a0, d, 64);
            a1 += __shfl_xor(a1, d, 64);
            a2 += __shfl_xor(a2, d, 64);
            a3 += __shfl_xor(a3, d, 64);
        }
    }
    if (s == 0) {
        float inv = (deg > 0) ? 1.f / l : 0.f;
        red[p][0] = a0 * inv; red[p][1] = a1 * inv;
        red[p][2] = a2 * inv; red[p][3] = a3 * inv;
    }
    __syncthreads();
    if (t < 64) {
        int bb = t >> 2, c = t & 3;
        float v = gbias[c];
        if (deg > 0)
            v += 0.5f * (red[bb * 2 + 0][c] + red[bb * 2 + 1][c]) / (float)deg;
        aggr[bb * (KC * KN) + c * KN + n] = v;
    }
}

// ---------------------------------------------------------------------------
// K6: readout. Block per (b,k): 16384-elem dot of lrelu(aggr[b]) with
// out_weight row k.
// ---------------------------------------------------------------------------
__global__ __launch_bounds__(256) void k6_out(const float* __restrict__ aggr,
                                              const float* __restrict__ ow,
                                              const float* __restrict__ obias,
                                              float* __restrict__ out) {
    int b = blockIdx.x >> 5;
    int k = blockIdx.x & 31;
    int t = threadIdx.x;
    const float* ar = aggr + (size_t)b * (KC * KN);
    const float* wr = ow + (size_t)k * (KC * KN);
    float sum = 0.f;
#pragma unroll 4
    for (int i = 0; i < 16; ++i) {
        int j = (i * 256 + t) * 4;
        float4 av = *(const float4*)(ar + j);
        float4 wv = *(const float4*)(wr + j);
        av.x = lrelu(av.x, 0.01f); av.y = lrelu(av.y, 0.01f);
        av.z = lrelu(av.z, 0.01f); av.w = lrelu(av.w, 0.01f);
        sum += av.x * wv.x + av.y * wv.y + av.z * wv.z + av.w * wv.w;
    }
#pragma unroll
    for (int d = 32; d > 0; d >>= 1) sum += __shfl_down(sum, d, 64);
    __shared__ float wsum[4];
    if ((t & 63) == 0) wsum[t >> 6] = sum;
    __syncthreads();
    if (t == 0) out[b * KOUT + k] = wsum[0] + wsum[1] + wsum[2] + wsum[3] + obias[k];
}

// ---------------------------------------------------------------------------
extern "C" void kernel_launch(void* const* d_in, const int* in_sizes, int n_in,
                              void* d_out, int out_size, void* d_ws, size_t ws_size,
                              hipStream_t stream) {
    const float* x     = (const float*)d_in[0];
    const int*   e32   = (const int*)d_in[1];
    const float* Wsub  = (const float*)d_in[2];
    const float* bsub  = (const float*)d_in[3];
    const float* fc1w  = (const float*)d_in[4];
    const float* maskr = (const float*)d_in[5];
    const float* fc1b  = (const float*)d_in[6];
    const float* gatw  = (const float*)d_in[7];
    const float* gata  = (const float*)d_in[8];
    const float* gatb  = (const float*)d_in[9];
    const float* outw  = (const float*)d_in[10];
    const float* outb  = (const float*)d_in[11];
    float* out = (float*)d_out;

    // Workspace layout (all 16-float aligned; ~6.2 MB total)
    float* ws   = (float*)d_ws;
    float* xcat = ws;                              // [B][G]        16384
    float* ht   = xcat + KB * KG;                  // [N][B][GO]    393216
    float* hn   = ht + (size_t)KN * KB * KGO;      // [N][B][H][C]  524288
    float* si   = hn + (size_t)KN * KB * KH * KC;  // [N][B][H]     131072
    float* sj   = si + (size_t)KN * KB * KH;       //               131072
    float* aggr = sj + (size_t)KN * KB * KH;       // [B][C][N]     262144
    int* icnt  = (int*)(aggr + (size_t)KB * KC * KN);  // N
    int* ioff  = icnt + KN;                            // N+1 (padded 16)
    int* icur  = ioff + (KN + 16);                     // N
    int* icsr  = icur + KN;                            // E
    int* iflag = icsr + KE;                            // 1

    k0_detect<<<1, 256, 0, stream>>>(e32, iflag);
    k1_subnet<<<(KB * KG) / 4, 256, 0, stream>>>(x, Wsub, bsub, xcat);
    k2_fc1<<<(KN * KGO) / 16, 256, 0, stream>>>(fc1w, maskr, fc1b, xcat, ht);
    k3_gatw<<<(KN * KB) / 256, 256, 0, stream>>>(ht, gatw, gata, hn, si, sj);
    hipMemsetAsync(icnt, 0, KN * sizeof(int), stream);
    k4a_hist<<<KE / 256, 256, 0, stream>>>(e32, iflag, icnt);
    k4b_scan<<<1, 1024, 0, stream>>>(icnt, ioff, icur);
    k4c_scatter<<<KE / 256, 256, 0, stream>>>(e32, iflag, icur, icsr);
    k5_gat<<<KN, 256, 0, stream>>>(ioff, icsr, si, sj, hn, gatb, aggr);
    k6_out<<<KB * KOUT, 256, 0, stream>>>(aggr, outw, outb, out);
}

// Round 2
// 557.746 us; speedup vs baseline: 1.0258x; 1.0258x over previous
//
#include <hip/hip_runtime.h>
#include <math.h>

// Problem constants (match reference)
#define KB 16      // batch
#define KT 256     // num_tf
#define KG 1024    // num_genes
#define KP 16      // peaks per gene
#define KN 4096    // num_gos
#define KGO 6      // go_dim
#define KH 2       // heads
#define KC 4       // out channels
#define KE 65536   // edges
#define KOUT 32    // num outputs

__device__ __forceinline__ float lrelu(float x, float s) { return x >= 0.f ? x : s * x; }

// ---------------------------------------------------------------------------
// K0: detect edge_index dtype. int64 little-endian with values <2^31 has all
// odd int32 words == 0. Writes flag=1 for int64 mode, 0 for int32.
// ---------------------------------------------------------------------------
__global__ __launch_bounds__(256) void k0_detect(const int* __restrict__ e32,
                                                 int* __restrict__ flag) {
    __shared__ int nz;
    if (threadIdx.x == 0) nz = 0;
    __syncthreads();
    int any = 0;
#pragma unroll
    for (int k = 0; k < 4; ++k) {
        int idx = (threadIdx.x * 4 + k) * 2 + 1;  // odd words of first 1024 entries
        any |= (e32[idx] != 0) ? 1 : 0;
    }
    if (any) atomicOr(&nz, 1);
    __syncthreads();
    if (threadIdx.x == 0) flag[0] = (nz == 0) ? 1 : 0;
}

// ---------------------------------------------------------------------------
// K1 (v2, streaming): per-gene subnet xcat[b][g] = lrelu(sum_{t,p} x*W + b).
// Block = (gene-chunk gc of 64 genes, batch b), 1024 threads = 4 t-quarters
// x 256 threads. Per t-iteration each quarter reads a CONTIGUOUS 4 KB
// segment of x (thread u -> float4 at x[b][t][g0*16 + 4u]) -- no 64 KB
// stride scatter (R1's channel-camping suspect). W_sub chunk (1 MB) is
// shared by the 16 consecutive b-blocks of a gc -> L2/L3 served.
// ---------------------------------------------------------------------------
__global__ __launch_bounds__(1024) void k1_subnet(const float* __restrict__ x,
                                                  const float* __restrict__ Wsub,
                                                  const float* __restrict__ bsub,
                                                  float* __restrict__ xcat) {
    int tid = threadIdx.x;
    int sub = tid >> 8;           // t-quarter 0..3
    int u   = tid & 255;
    int gc  = blockIdx.x >> 4;    // 0..15  (gc-major: 16 b-blocks share W chunk)
    int b   = blockIdx.x & 15;
    int g0  = gc * 64;
    int g   = g0 + (u >> 2);
    int p4  = (u & 3) * 4;
    const float* xb = x + (size_t)b * (KT * KG * KP) + (size_t)g0 * KP + u * 4;
    const float* wg = Wsub + (size_t)g * (KT * KP) + p4;
    float4 acc = make_float4(0.f, 0.f, 0.f, 0.f);
    int t0 = sub * 64;
#pragma unroll 4
    for (int i = 0; i < 64; ++i) {
        int t = t0 + i;
        float4 xv = *(const float4*)(xb + (size_t)t * (KG * KP));
        float4 wv = *(const float4*)(wg + (size_t)t * KP);
        acc.x += xv.x * wv.x; acc.y += xv.y * wv.y;
        acc.z += xv.z * wv.z; acc.w += xv.w * wv.w;
    }
    float s = acc.x + acc.y + acc.z + acc.w;
    s += __shfl_xor(s, 1, 64);
    s += __shfl_xor(s, 2, 64);    // quad-reduce: 4 lanes of one gene
    __shared__ float part[4][64];
    if ((u & 3) == 0) part[sub][u >> 2] = s;
    __syncthreads();
    if (tid < 64) {
        float v = part[0][tid] + part[1][tid] + part[2][tid] + part[3][tid];
        xcat[b * KG + g0 + tid] = lrelu(v + bsub[g0 + tid], 0.01f);
    }
}

// ---------------------------------------------------------------------------
// K2: masked fc1 (the 200 MB stream). Block = 4 waves; wave `wid` owns batches
// b0=wid*4..+3 and preloads its x_cat slice into registers ONCE. Inner loop
// per row j: two coalesced float4 streams (w, mask), 64 FMAs, cross-lane
// shfl reduce. No LDS. 4 waves share w rows -> L1 hits, HBM reads w once.
// ---------------------------------------------------------------------------
__global__ __launch_bounds__(256) void k2_fc1(const float* __restrict__ w,
                                              const float* __restrict__ mask,
                                              const float* __restrict__ bias,
                                              const float* __restrict__ xcat, // [b][g]
                                              float* __restrict__ ht) {      // [n][b][d]
    int wid = threadIdx.x >> 6;
    int lane = threadIdx.x & 63;
    int b0 = wid * 4;
    float4 xcr[4][4];  // [bb][i] -> x_cat[b0+bb][i*256 + lane*4 .. +3]
#pragma unroll
    for (int bb = 0; bb < 4; ++bb)
#pragma unroll
        for (int i = 0; i < 4; ++i)
            xcr[bb][i] = *(const float4*)(xcat + (b0 + bb) * KG + i * 256 + lane * 4);

    for (int r = 0; r < 16; ++r) {
        int j = blockIdx.x * 16 + r;        // row of (w*mask), j < 24576
        const float* wr = w + (size_t)j * KG;
        const float* mr = mask + (size_t)j * KG;
        float acc0 = 0.f, acc1 = 0.f, acc2 = 0.f, acc3 = 0.f;
#pragma unroll
        for (int i = 0; i < 4; ++i) {
            float4 wv = *(const float4*)(wr + i * 256 + lane * 4);
            float4 mv = *(const float4*)(mr + i * 256 + lane * 4);
            float px = wv.x * mv.x, py = wv.y * mv.y, pz = wv.z * mv.z, pw = wv.w * mv.w;
            acc0 += px * xcr[0][i].x + py * xcr[0][i].y + pz * xcr[0][i].z + pw * xcr[0][i].w;
            acc1 += px * xcr[1][i].x + py * xcr[1][i].y + pz * xcr[1][i].z + pw * xcr[1][i].w;
            acc2 += px * xcr[2][i].x + py * xcr[2][i].y + pz * xcr[2][i].z + pw * xcr[2][i].w;
            acc3 += px * xcr[3][i].x + py * xcr[3][i].y + pz * xcr[3][i].z + pw * xcr[3][i].w;
        }
#pragma unroll
        for (int m = 1; m < 64; m <<= 1) {
            acc0 += __shfl_xor(acc0, m, 64);
            acc1 += __shfl_xor(acc1, m, 64);
            acc2 += __shfl_xor(acc2, m, 64);
            acc3 += __shfl_xor(acc3, m, 64);
        }
        if (lane == 0) {
            float bj = bias[j];
            int d = j >> 12;           // j / N
            int n = j & 4095;          // j % N
            float* hp = ht + ((size_t)n * KB) * KGO + d;
            hp[(b0 + 0) * KGO] = lrelu(acc0 + bj, 0.01f);
            hp[(b0 + 1) * KGO] = lrelu(acc1 + bj, 0.01f);
            hp[(b0 + 2) * KGO] = lrelu(acc2 + bj, 0.01f);
            hp[(b0 + 3) * KGO] = lrelu(acc3 + bj, 0.01f);
        }
    }
}

// ---------------------------------------------------------------------------
// K3: hn = h @ gat_weight, plus attention dot products s_i, s_j per node.
// One thread per (n,b).
// ---------------------------------------------------------------------------
__global__ __launch_bounds__(256) void k3_gatw(const float* __restrict__ ht,
                                               const float* __restrict__ gw,   // [6][8]
                                               const float* __restrict__ att,  // [2][8]
                                               float* __restrict__ hn,         // [n][b][h][c]
                                               float* __restrict__ si,
                                               float* __restrict__ sj) {
    __shared__ float cgw[48];
    __shared__ float catt[16];
    int t = threadIdx.x;
    if (t < 48) cgw[t] = gw[t];
    else if (t < 64) catt[t - 48] = att[t - 48];
    __syncthreads();
    int idx = blockIdx.x * 256 + t;  // n*16 + b
    float h6[6];
#pragma unroll
    for (int d = 0; d < 6; ++d) h6[d] = ht[(size_t)idx * KGO + d];
    float o[8];
#pragma unroll
    for (int hc = 0; hc < 8; ++hc) {
        float v = 0.f;
#pragma unroll
        for (int d = 0; d < 6; ++d) v += h6[d] * cgw[d * 8 + hc];
        o[hc] = v;
        hn[(size_t)idx * 8 + hc] = v;
    }
#pragma unroll
    for (int hh = 0; hh < 2; ++hh) {
        float vi = 0.f, vj = 0.f;
#pragma unroll
        for (int c = 0; c < 4; ++c) {
            vi += o[hh * 4 + c] * catt[hh * 8 + c];       // att[:, :C]  (x_i)
            vj += o[hh * 4 + c] * catt[hh * 8 + 4 + c];   // att[:, C:]  (x_j)
        }
        si[idx * 2 + hh] = vi;
        sj[idx * 2 + hh] = vj;
    }
}

// ---------------------------------------------------------------------------
// K4a/b/c: CSR build (histogram, exclusive scan, scatter)
// ---------------------------------------------------------------------------
__global__ __launch_bounds__(256) void k4a_hist(const int* __restrict__ e32,
                                                const int* __restrict__ flag,
                                                int* __restrict__ cnt) {
    int e = blockIdx.x * 256 + threadIdx.x;
    int mode = flag[0];
    int d = mode ? e32[2 * (KE + e)] : e32[KE + e];
    atomicAdd(&cnt[d], 1);
}

__global__ __launch_bounds__(1024) void k4b_scan(const int* __restrict__ cnt,
                                                 int* __restrict__ off,
                                                 int* __restrict__ cur) {
    __shared__ int buf[2][1024];
    int t = threadIdx.x;
    int c0 = cnt[t * 4 + 0], c1 = cnt[t * 4 + 1], c2 = cnt[t * 4 + 2], c3 = cnt[t * 4 + 3];
    int s = c0 + c1 + c2 + c3;
    buf[0][t] = s;
    __syncthreads();
    int pb = 0;
    for (int d = 1; d < 1024; d <<= 1) {
        int v = buf[pb][t];
        if (t >= d) v += buf[pb][t - d];
        buf[1 - pb][t] = v;
        pb = 1 - pb;
        __syncthreads();
    }
    int incl = buf[pb][t];
    int base = incl - s;  // exclusive prefix
    int o0 = base, o1 = base + c0, o2 = base + c0 + c1, o3 = base + c0 + c1 + c2;
    off[t * 4 + 0] = o0; off[t * 4 + 1] = o1; off[t * 4 + 2] = o2; off[t * 4 + 3] = o3;
    cur[t * 4 + 0] = o0; cur[t * 4 + 1] = o1; cur[t * 4 + 2] = o2; cur[t * 4 + 3] = o3;
    if (t == 1023) off[KN] = incl;
}

__global__ __launch_bounds__(256) void k4c_scatter(const int* __restrict__ e32,
                                                   const int* __restrict__ flag,
                                                   int* __restrict__ cur,
                                                   int* __restrict__ csr) {
    int e = blockIdx.x * 256 + threadIdx.x;
    int mode = flag[0];
    int d = mode ? e32[2 * (KE + e)] : e32[KE + e];
    int s = mode ? e32[2 * e] : e32[e];
    int p = atomicAdd(&cur[d], 1);
    csr[p] = s;
}

// ---------------------------------------------------------------------------
// K5: per-destination-node GAT aggregation. Block per node n; thread groups
// of 8 own one (b,h) pair. Pass 1: segment max (exact, like reference).
// Pass 2: exp-sum + weighted accumulation of hn[src]. Softmax-normalize,
// divide by degree, mean over heads, + bias. Output aggr[b][c*N + n].
// ---------------------------------------------------------------------------
__global__ __launch_bounds__(256) void k5_gat(const int* __restrict__ offs,
                                              const int* __restrict__ csr,
                                              const float* __restrict__ si,
                                              const float* __restrict__ sj,
                                              const float* __restrict__ hn,
                                              const float* __restrict__ gbias,
                                              float* __restrict__ aggr) {
    int n = blockIdx.x;
    int t = threadIdx.x;
    int p = t >> 3;          // (b,h) pair, 0..31
    int s = t & 7;
    int b = p >> 1, h = p & 1;
    int off = offs[n];
    int deg = offs[n + 1] - off;
    __shared__ float red[32][4];
    float l = 0.f, a0 = 0.f, a1 = 0.f, a2 = 0.f, a3 = 0.f;
    if (deg > 0) {
        float sib = si[(n * KB + b) * 2 + h];
        float m = -1e30f;
        for (int i = s; i < deg; i += 8) {
            int sv = csr[off + i];
            float a = sib + sj[(sv * KB + b) * 2 + h];
            a = a >= 0.f ? a : 0.2f * a;
            m = fmaxf(m, a);
        }
        m = fmaxf(m, __shfl_xor(m, 1, 64));
        m = fmaxf(m, __shfl_xor(m, 2, 64));
        m = fmaxf(m, __shfl_xor(m, 4, 64));
        for (int i = s; i < deg; i += 8) {
            int sv = csr[off + i];
            float a = sib + sj[(sv * KB + b) * 2 + h];
            a = a >= 0.f ? a : 0.2f * a;
            float wgt = expf(a - m);
            l += wgt;
            float4 hv = *(const float4*)(hn + ((size_t)(sv * KB + b)) * 8 + h * 4);
            a0 += wgt * hv.x; a1 += wgt * hv.y; a2 += wgt * hv.z; a3 += wgt * hv.w;
        }
#pragma unroll
        for (int d = 1; d <= 4; d <<= 1) {
            l  += __shfl_xor(l,  d, 64);
            a0 += __shfl_xor(a0, d, 64);
            a1 += __shfl_xor(a1, d, 64);
            a2 += __shfl_xor(a2, d, 64);
            a3 += __shfl_xor(a3, d, 64);
        }
    }
    if (s == 0) {
        float inv = (deg > 0) ? 1.f / l : 0.f;
        red[p][0] = a0 * inv; red[p][1] = a1 * inv;
        red[p][2] = a2 * inv; red[p][3] = a3 * inv;
    }
    __syncthreads();
    if (t < 64) {
        int bb = t >> 2, c = t & 3;
        float v = gbias[c];
        if (deg > 0)
            v += 0.5f * (red[bb * 2 + 0][c] + red[bb * 2 + 1][c]) / (float)deg;
        aggr[bb * (KC * KN) + c * KN + n] = v;
    }
}

// ---------------------------------------------------------------------------
// K6: readout. Block per (b,k): 16384-elem dot of lrelu(aggr[b]) with
// out_weight row k.
// ---------------------------------------------------------------------------
__global__ __launch_bounds__(256) void k6_out(const float* __restrict__ aggr,
                                              const float* __restrict__ ow,
                                              const float* __restrict__ obias,
                                              float* __restrict__ out) {
    int b = blockIdx.x >> 5;
    int k = blockIdx.x & 31;
    int t = threadIdx.x;
    const float* ar = aggr + (size_t)b * (KC * KN);
    const float* wr = ow + (size_t)k * (KC * KN);
    float sum = 0.f;
#pragma unroll 4
    for (int i = 0; i < 16; ++i) {
        int j = (i * 256 + t) * 4;
        float4 av = *(const float4*)(ar + j);
        float4 wv = *(const float4*)(wr + j);
        av.x = lrelu(av.x, 0.01f); av.y = lrelu(av.y, 0.01f);
        av.z = lrelu(av.z, 0.01f); av.w = lrelu(av.w, 0.01f);
        sum += av.x * wv.x + av.y * wv.y + av.z * wv.z + av.w * wv.w;
    }
#pragma unroll
    for (int d = 32; d > 0; d >>= 1) sum += __shfl_down(sum, d, 64);
    __shared__ float wsum[4];
    if ((t & 63) == 0) wsum[t >> 6] = sum;
    __syncthreads();
    if (t == 0) out[b * KOUT + k] = wsum[0] + wsum[1] + wsum[2] + wsum[3] + obias[k];
}

// ---------------------------------------------------------------------------
extern "C" void kernel_launch(void* const* d_in, const int* in_sizes, int n_in,
                              void* d_out, int out_size, void* d_ws, size_t ws_size,
                              hipStream_t stream) {
    const float* x     = (const float*)d_in[0];
    const int*   e32   = (const int*)d_in[1];
    const float* Wsub  = (const float*)d_in[2];
    const float* bsub  = (const float*)d_in[3];
    const float* fc1w  = (const float*)d_in[4];
    const float* maskr = (const float*)d_in[5];
    const float* fc1b  = (const float*)d_in[6];
    const float* gatw  = (const float*)d_in[7];
    const float* gata  = (const float*)d_in[8];
    const float* gatb  = (const float*)d_in[9];
    const float* outw  = (const float*)d_in[10];
    const float* outb  = (const float*)d_in[11];
    float* out = (float*)d_out;

    // Workspace layout (all 16-float aligned; ~6.2 MB total)
    float* ws   = (float*)d_ws;
    float* xcat = ws;                              // [B][G]        16384
    float* ht   = xcat + KB * KG;                  // [N][B][GO]    393216
    float* hn   = ht + (size_t)KN * KB * KGO;      // [N][B][H][C]  524288
    float* si   = hn + (size_t)KN * KB * KH * KC;  // [N][B][H]     131072
    float* sj   = si + (size_t)KN * KB * KH;       //               131072
    float* aggr = sj + (size_t)KN * KB * KH;       // [B][C][N]     262144
    int* icnt  = (int*)(aggr + (size_t)KB * KC * KN);  // N
    int* ioff  = icnt + KN;                            // N+1 (padded 16)
    int* icur  = ioff + (KN + 16);                     // N
    int* icsr  = icur + KN;                            // E
    int* iflag = icsr + KE;                            // 1

    k0_detect<<<1, 256, 0, stream>>>(e32, iflag);
    k1_subnet<<<256, 1024, 0, stream>>>(x, Wsub, bsub, xcat);
    k2_fc1<<<(KN * KGO) / 16, 256, 0, stream>>>(fc1w, maskr, fc1b, xcat, ht);
    k3_gatw<<<(KN * KB) / 256, 256, 0, stream>>>(ht, gatw, gata, hn, si, sj);
    hipMemsetAsync(icnt, 0, KN * sizeof(int), stream);
    k4a_hist<<<KE / 256, 256, 0, stream>>>(e32, iflag, icnt);
    k4b_scan<<<1, 1024, 0, stream>>>(icnt, ioff, icur);
    k4c_scatter<<<KE / 256, 256, 0, stream>>>(e32, iflag, icur, icsr);
    k5_gat<<<KN, 256, 0, stream>>>(ioff, icsr, si, sj, hn, gatb, aggr);
    k6_out<<<KB * KOUT, 256, 0, stream>>>(aggr, outw, outb, out);
}